// Round 6
// baseline (708.486 us; speedup 1.0000x reference)
//
#include <hip/hip_runtime.h>
#include <math.h>

#define NNODES 20000
#define NEDGES 320000
#define CC 128          // channels
#define TC 384          // 3*C
#define BB 20           // basis dim
#define RCUT_F 5.0f
#define PI_F 3.14159265358979323846f
#define PKF 28          // packed floats per edge (112 B, float4-aligned)

// ---------------------------------------------------------------------------
// CSR build: zero -> histogram -> single-block scan -> pack+scatter
// ---------------------------------------------------------------------------
__global__ __launch_bounds__(256) void zero_counts_kernel(int* __restrict__ counts) {
  const int i = blockIdx.x * 256 + threadIdx.x;
  if (i < NNODES) counts[i] = 0;
}

__global__ __launch_bounds__(256) void hist_kernel(const int* __restrict__ eidx,
                                                   int* __restrict__ counts) {
  const int e = blockIdx.x * 256 + threadIdx.x;
  if (e < NEDGES) atomicAdd(&counts[eidx[e]], 1);
}

__global__ __launch_bounds__(512) void scan_kernel(int* __restrict__ counts,
                                                   int* __restrict__ offsets) {
  __shared__ int sums[512];
  const int t = threadIdx.x;
  const int chunk = 40;                       // ceil(20000/512)
  const int lo = t * chunk;
  const int hi = min(lo + chunk, NNODES);
  int s = 0;
  for (int i = lo; i < hi; ++i) s += counts[i];
  sums[t] = s;
  __syncthreads();
  for (int d = 1; d < 512; d <<= 1) {
    const int other = (t >= d) ? sums[t - d] : 0;
    __syncthreads();
    sums[t] += other;
    __syncthreads();
  }
  int run = sums[t] - s;                      // exclusive prefix
  for (int i = lo; i < hi; ++i) {
    offsets[i] = run;
    run += counts[i];
    counts[i] = 0;                            // re-zero: reused as scatter cursor
  }
  if (hi == NNODES) offsets[NNODES] = run;    // == NEDGES
}

// packed[pos] = { j(bits), fc, v0, v1, v2, fc*attrs[0..19], pad[3] }
__global__ __launch_bounds__(256) void pack_scatter_kernel(
    const int* __restrict__ eidx, const float* __restrict__ ew,
    const float* __restrict__ evers, const float* __restrict__ eattr,
    const int* __restrict__ offsets, int* __restrict__ counts,
    float* __restrict__ packed) {
  const int e = blockIdx.x * 256 + threadIdx.x;
  if (e >= NEDGES) return;
  const int i = eidx[e];
  const int j = eidx[NEDGES + e];
  const int pos = offsets[i] + atomicAdd(&counts[i], 1);
  const float w = ew[e];
  const float fc = (w < RCUT_F)
      ? 0.5f * (cosf(PI_F * (1.0f / RCUT_F) * w) + 1.0f) : 0.0f;
  float* p = packed + (size_t)pos * PKF;
  p[0] = __int_as_float(j);
  p[1] = fc;
  p[2] = evers[(size_t)e * 3];
  p[3] = evers[(size_t)e * 3 + 1];
  p[4] = evers[(size_t)e * 3 + 2];
  const float* ae = eattr + (size_t)e * BB;
  #pragma unroll
  for (int b = 0; b < BB; ++b) p[5 + b] = fc * ae[b];
}

// fallback (no packing) scatter for small ws
__global__ __launch_bounds__(256) void scatter_kernel(const int* __restrict__ eidx,
                                                      const int* __restrict__ offsets,
                                                      int* __restrict__ counts,
                                                      int* __restrict__ edge_list) {
  const int e = blockIdx.x * 256 + threadIdx.x;
  if (e < NEDGES) {
    const int i = eidx[e];
    const int pos = offsets[i] + atomicAdd(&counts[i], 1);
    edge_list[pos] = e;
  }
}

// ---------------------------------------------------------------------------
// Context net v2: x = silu(q@W1 + b1) @ W2 + b2      [N, 3C]
// 8 nodes per block, 128 threads. GEMM1 activations read UNIFORMLY from
// global q (const input -> scalar/L1 broadcast, no LDS pipe). Only the
// distributed intermediate h stays in LDS.
// ---------------------------------------------------------------------------
#define CNPB 8
__global__ __launch_bounds__(128) void ctx_net_kernel(
    const float* __restrict__ q,
    const float* __restrict__ W1, const float* __restrict__ b1,
    const float* __restrict__ W2, const float* __restrict__ b2,
    float* __restrict__ x) {
  __shared__ __align__(16) float h_lds[CNPB][CC];
  const int t = threadIdx.x;
  const int node0 = blockIdx.x * CNPB;

  float acc[CNPB];
  {
    const float bv = b1[t];
    #pragma unroll
    for (int n = 0; n < CNPB; ++n) acc[n] = bv;
  }
  for (int k = 0; k < CC; k += 8) {
    float w[8];
    #pragma unroll
    for (int r = 0; r < 8; ++r) w[r] = W1[(size_t)(k + r) * CC + t];
    #pragma unroll
    for (int n = 0; n < CNPB; ++n) {
      const float* qrow = q + (size_t)(node0 + n) * CC + k;   // uniform addr
      const float4 q0 = *reinterpret_cast<const float4*>(qrow);
      const float4 q1 = *reinterpret_cast<const float4*>(qrow + 4);
      acc[n] = fmaf(q0.x, w[0], acc[n]); acc[n] = fmaf(q0.y, w[1], acc[n]);
      acc[n] = fmaf(q0.z, w[2], acc[n]); acc[n] = fmaf(q0.w, w[3], acc[n]);
      acc[n] = fmaf(q1.x, w[4], acc[n]); acc[n] = fmaf(q1.y, w[5], acc[n]);
      acc[n] = fmaf(q1.z, w[6], acc[n]); acc[n] = fmaf(q1.w, w[7], acc[n]);
    }
  }
  #pragma unroll
  for (int n = 0; n < CNPB; ++n) {
    const float v = acc[n];
    h_lds[n][t] = v / (1.0f + expf(-v));
  }
  __syncthreads();

  float y0[CNPB], y1[CNPB], y2[CNPB];
  {
    const float bb0 = b2[t], bb1 = b2[CC + t], bb2 = b2[2 * CC + t];
    #pragma unroll
    for (int n = 0; n < CNPB; ++n) { y0[n] = bb0; y1[n] = bb1; y2[n] = bb2; }
  }
  for (int k = 0; k < CC; k += 8) {
    float w0[8], w1[8], w2[8];
    #pragma unroll
    for (int r = 0; r < 8; ++r) {
      const size_t row = (size_t)(k + r) * TC;
      w0[r] = W2[row + t];
      w1[r] = W2[row + CC + t];
      w2[r] = W2[row + 2 * CC + t];
    }
    #pragma unroll
    for (int n = 0; n < CNPB; ++n) {
      const float4 h0 = *reinterpret_cast<const float4*>(&h_lds[n][k]);
      const float4 h1 = *reinterpret_cast<const float4*>(&h_lds[n][k + 4]);
      y0[n] = fmaf(h0.x, w0[0], y0[n]); y0[n] = fmaf(h0.y, w0[1], y0[n]);
      y0[n] = fmaf(h0.z, w0[2], y0[n]); y0[n] = fmaf(h0.w, w0[3], y0[n]);
      y0[n] = fmaf(h1.x, w0[4], y0[n]); y0[n] = fmaf(h1.y, w0[5], y0[n]);
      y0[n] = fmaf(h1.z, w0[6], y0[n]); y0[n] = fmaf(h1.w, w0[7], y0[n]);
      y1[n] = fmaf(h0.x, w1[0], y1[n]); y1[n] = fmaf(h0.y, w1[1], y1[n]);
      y1[n] = fmaf(h0.z, w1[2], y1[n]); y1[n] = fmaf(h0.w, w1[3], y1[n]);
      y1[n] = fmaf(h1.x, w1[4], y1[n]); y1[n] = fmaf(h1.y, w1[5], y1[n]);
      y1[n] = fmaf(h1.z, w1[6], y1[n]); y1[n] = fmaf(h1.w, w1[7], y1[n]);
      y2[n] = fmaf(h0.x, w2[0], y2[n]); y2[n] = fmaf(h0.y, w2[1], y2[n]);
      y2[n] = fmaf(h0.z, w2[2], y2[n]); y2[n] = fmaf(h0.w, w2[3], y2[n]);
      y2[n] = fmaf(h1.x, w2[4], y2[n]); y2[n] = fmaf(h1.y, w2[5], y2[n]);
      y2[n] = fmaf(h1.z, w2[6], y2[n]); y2[n] = fmaf(h1.w, w2[7], y2[n]);
    }
  }
  #pragma unroll
  for (int n = 0; n < CNPB; ++n) {
    const size_t base = (size_t)(node0 + n) * TC;
    x[base + t]          = y0[n];
    x[base + CC + t]     = y1[n];
    x[base + 2 * CC + t] = y2[n];
  }
}

// ---------------------------------------------------------------------------
// Gather (packed path): one block of 384 threads per node; thread c owns
// filter column c (weights in 20 regs). Unrolled x2 for MLP of the
// dependent gather chain. Writes q+dq / mu+dmu to d_out.
// ---------------------------------------------------------------------------
#define GTH 384

struct EdgeRegs { float4 h0, h1, h2, h3, h4, h5, h6; };

__device__ __forceinline__ EdgeRegs load_edge(const float4* __restrict__ p4,
                                              int k) {
  const float4* p = p4 + (size_t)k * (PKF / 4);
  EdgeRegs E;
  E.h0 = p[0]; E.h1 = p[1]; E.h2 = p[2]; E.h3 = p[3];
  E.h4 = p[4]; E.h5 = p[5]; E.h6 = p[6];
  return E;
}

__device__ __forceinline__ float filter_ws(const EdgeRegs& E,
                                           const float* wreg, float bfc) {
  float ws = E.h0.y * bfc;                    // fc * bf[c]
  ws = fmaf(E.h1.y, wreg[0], ws);  ws = fmaf(E.h1.z, wreg[1], ws);
  ws = fmaf(E.h1.w, wreg[2], ws);  ws = fmaf(E.h2.x, wreg[3], ws);
  ws = fmaf(E.h2.y, wreg[4], ws);  ws = fmaf(E.h2.z, wreg[5], ws);
  ws = fmaf(E.h2.w, wreg[6], ws);  ws = fmaf(E.h3.x, wreg[7], ws);
  ws = fmaf(E.h3.y, wreg[8], ws);  ws = fmaf(E.h3.z, wreg[9], ws);
  ws = fmaf(E.h3.w, wreg[10], ws); ws = fmaf(E.h4.x, wreg[11], ws);
  ws = fmaf(E.h4.y, wreg[12], ws); ws = fmaf(E.h4.z, wreg[13], ws);
  ws = fmaf(E.h4.w, wreg[14], ws); ws = fmaf(E.h5.x, wreg[15], ws);
  ws = fmaf(E.h5.y, wreg[16], ws); ws = fmaf(E.h5.z, wreg[17], ws);
  ws = fmaf(E.h5.w, wreg[18], ws); ws = fmaf(E.h6.x, wreg[19], ws);
  return ws;
}

__global__ __launch_bounds__(GTH) void gather_packed_kernel(
    const float* __restrict__ packed,
    const float* __restrict__ Wf, const float* __restrict__ bf,
    const float* __restrict__ x, const float* __restrict__ mu_in,
    const float* __restrict__ q_in, const int* __restrict__ offsets,
    float* __restrict__ qout, float* __restrict__ muout) {
  __shared__ float red[3][CC];
  const int c = threadIdx.x;
  const int i = blockIdx.x;
  const int grp = c >> 7;          // wave-uniform
  const int ch = c & 127;

  float wreg[BB];
  #pragma unroll
  for (int b = 0; b < BB; ++b) wreg[b] = Wf[b * TC + c];
  const float bfc = bf[c];

  const float4* p4 = reinterpret_cast<const float4*>(packed);
  const int start = offsets[i];
  const int end = offsets[i + 1];
  float a0 = 0.f, a1 = 0.f, a2 = 0.f;

  int k = start;
  for (; k + 1 < end; k += 2) {
    const EdgeRegs A = load_edge(p4, k);
    const EdgeRegs B = load_edge(p4, k + 1);
    const int jA = __float_as_int(A.h0.x);
    const int jB = __float_as_int(B.h0.x);
    const float xA = x[(size_t)jA * TC + c];
    const float xB = x[(size_t)jB * TC + c];
    float muA0, muA1, muA2, muB0, muB1, muB2;
    if (grp == 2) {
      const float* mA = mu_in + (size_t)jA * TC + ch;
      const float* mB = mu_in + (size_t)jB * TC + ch;
      muA0 = mA[0]; muA1 = mA[CC]; muA2 = mA[2 * CC];
      muB0 = mB[0]; muB1 = mB[CC]; muB2 = mB[2 * CC];
    }
    const float wsA = filter_ws(A, wreg, bfc);
    const float wsB = filter_ws(B, wreg, bfc);
    const float xvA = xA * wsA;
    const float xvB = xB * wsB;
    if (grp == 0) {
      a0 += xvA + xvB;
    } else if (grp == 1) {
      a0 = fmaf(xvA, A.h0.z, fmaf(xvB, B.h0.z, a0));
      a1 = fmaf(xvA, A.h0.w, fmaf(xvB, B.h0.w, a1));
      a2 = fmaf(xvA, A.h1.x, fmaf(xvB, B.h1.x, a2));
    } else {
      a0 = fmaf(xvA, muA0, fmaf(xvB, muB0, a0));
      a1 = fmaf(xvA, muA1, fmaf(xvB, muB1, a1));
      a2 = fmaf(xvA, muA2, fmaf(xvB, muB2, a2));
    }
  }
  if (k < end) {
    const EdgeRegs A = load_edge(p4, k);
    const int jA = __float_as_int(A.h0.x);
    const float xA = x[(size_t)jA * TC + c];
    const float wsA = filter_ws(A, wreg, bfc);
    const float xvA = xA * wsA;
    if (grp == 0) {
      a0 += xvA;
    } else if (grp == 1) {
      a0 = fmaf(xvA, A.h0.z, a0);
      a1 = fmaf(xvA, A.h0.w, a1);
      a2 = fmaf(xvA, A.h1.x, a2);
    } else {
      const float* mA = mu_in + (size_t)jA * TC + ch;
      a0 = fmaf(xvA, mA[0], a0);
      a1 = fmaf(xvA, mA[CC], a1);
      a2 = fmaf(xvA, mA[2 * CC], a2);
    }
  }

  if (grp == 1) { red[0][ch] = a0; red[1][ch] = a1; red[2][ch] = a2; }
  __syncthreads();

  if (grp == 0) {
    qout[(size_t)i * CC + ch] = q_in[(size_t)i * CC + ch] + a0;
  } else if (grp == 2) {
    const size_t mb = (size_t)i * TC;
    muout[mb + ch]          = mu_in[mb + ch]          + red[0][ch] + a0;
    muout[mb + CC + ch]     = mu_in[mb + CC + ch]     + red[1][ch] + a1;
    muout[mb + 2 * CC + ch] = mu_in[mb + 2 * CC + ch] + red[2][ch] + a2;
  }
}

// fallback gather (edge_list indirection) for small ws
__global__ __launch_bounds__(GTH) void gather_list_kernel(
    const int* __restrict__ eidx, const float* __restrict__ ew,
    const float* __restrict__ evers, const float* __restrict__ eattr,
    const float* __restrict__ Wf, const float* __restrict__ bf,
    const float* __restrict__ x, const float* __restrict__ mu_in,
    const float* __restrict__ q_in,
    const int* __restrict__ offsets, const int* __restrict__ edge_list,
    float* __restrict__ qout, float* __restrict__ muout) {
  __shared__ float red[3][CC];
  const int c = threadIdx.x;
  const int i = blockIdx.x;
  const int grp = c >> 7;
  const int ch = c & 127;
  float wreg[BB];
  #pragma unroll
  for (int b = 0; b < BB; ++b) wreg[b] = Wf[b * TC + c];
  const float bfc = bf[c];
  const int start = offsets[i];
  const int end = offsets[i + 1];
  float a0 = 0.f, a1 = 0.f, a2 = 0.f;
  for (int k = start; k < end; ++k) {
    const int e = edge_list[k];
    const int j = eidx[NEDGES + e];
    const float w = ew[e];
    const float fc = (w < RCUT_F)
        ? 0.5f * (cosf(PI_F * (1.0f / RCUT_F) * w) + 1.0f) : 0.0f;
    const float2* ae2 = reinterpret_cast<const float2*>(eattr + (size_t)e * BB);
    float wsum = bfc;
    #pragma unroll
    for (int b = 0; b < BB / 2; ++b) {
      const float2 a = ae2[b];
      wsum = fmaf(a.x, wreg[2 * b], wsum);
      wsum = fmaf(a.y, wreg[2 * b + 1], wsum);
    }
    wsum *= fc;
    const float xv = x[(size_t)j * TC + c] * wsum;
    if (grp == 0) {
      a0 += xv;
    } else if (grp == 1) {
      const float v0 = evers[(size_t)e * 3];
      const float v1 = evers[(size_t)e * 3 + 1];
      const float v2 = evers[(size_t)e * 3 + 2];
      a0 = fmaf(xv, v0, a0); a1 = fmaf(xv, v1, a1); a2 = fmaf(xv, v2, a2);
    } else {
      const float* muj = mu_in + (size_t)j * TC + ch;
      a0 = fmaf(xv, muj[0], a0);
      a1 = fmaf(xv, muj[CC], a1);
      a2 = fmaf(xv, muj[2 * CC], a2);
    }
  }
  if (grp == 1) { red[0][ch] = a0; red[1][ch] = a1; red[2][ch] = a2; }
  __syncthreads();
  if (grp == 0) {
    qout[(size_t)i * CC + ch] = q_in[(size_t)i * CC + ch] + a0;
  } else if (grp == 2) {
    const size_t mb = (size_t)i * TC;
    muout[mb + ch]          = mu_in[mb + ch]          + red[0][ch] + a0;
    muout[mb + CC + ch]     = mu_in[mb + CC + ch]     + red[1][ch] + a1;
    muout[mb + 2 * CC + ch] = mu_in[mb + 2 * CC + ch] + red[2][ch] + a2;
  }
}

// ---------------------------------------------------------------------------
// Mixing v2: 8 nodes per block, 128 threads. Activations (qnew/munew, written
// by gather into d_out) are read via read-only __restrict__ views with
// wave-UNIFORM addresses -> VMEM/scalar broadcast, no LDS staging. Only the
// distributed intermediates (mu_V norm, h2) round-trip through 8 KB LDS.
// Every aliased load feeds the value of its matching store (data dep), so
// ordering is safe. Occupancy: ~88 VGPR, 8 KB LDS -> ~8-10 blocks/CU.
// ---------------------------------------------------------------------------
#define MNPB 8
__global__ __launch_bounds__(128) void mix_kernel2(
    const float* __restrict__ Wmix, const float* __restrict__ Wm1,
    const float* __restrict__ bm1, const float* __restrict__ Wm2,
    const float* __restrict__ bm2,
    const float* __restrict__ actq,   // read-only view of qout
    const float* __restrict__ actmu,  // read-only view of muout
    float* __restrict__ qout, float* __restrict__ muout) {
  __shared__ __align__(16) float vn_lds[MNPB][CC];  // 4 KB
  __shared__ __align__(16) float h2_lds[MNPB][CC];  // 4 KB

  const int t = threadIdx.x;
  const int node0 = blockIdx.x * MNPB;

  // ---- mu_mix: thread t owns mu_V col t and mu_W col t ----
  float mW[MNPB][3], sdot[MNPB];
  {
    float mV[MNPB][3];
    #pragma unroll
    for (int n = 0; n < MNPB; ++n)
      #pragma unroll
      for (int v = 0; v < 3; ++v) { mV[n][v] = 0.0f; mW[n][v] = 0.0f; }

    for (int c = 0; c < CC; c += 8) {
      float wv[8], ww[8];
      #pragma unroll
      for (int r = 0; r < 8; ++r) {
        const size_t row = (size_t)(c + r) * (2 * CC);
        wv[r] = Wmix[row + t];
        ww[r] = Wmix[row + CC + t];
      }
      #pragma unroll
      for (int n = 0; n < MNPB; ++n) {
        #pragma unroll
        for (int v = 0; v < 3; ++v) {
          const float* mrow = actmu + ((size_t)(node0 + n) * 3 + v) * CC + c;
          const float4 m0 = *reinterpret_cast<const float4*>(mrow);      // uniform
          const float4 m1 = *reinterpret_cast<const float4*>(mrow + 4);  // uniform
          float a = mV[n][v], b = mW[n][v];
          a = fmaf(m0.x, wv[0], a); a = fmaf(m0.y, wv[1], a);
          a = fmaf(m0.z, wv[2], a); a = fmaf(m0.w, wv[3], a);
          a = fmaf(m1.x, wv[4], a); a = fmaf(m1.y, wv[5], a);
          a = fmaf(m1.z, wv[6], a); a = fmaf(m1.w, wv[7], a);
          b = fmaf(m0.x, ww[0], b); b = fmaf(m0.y, ww[1], b);
          b = fmaf(m0.z, ww[2], b); b = fmaf(m0.w, ww[3], b);
          b = fmaf(m1.x, ww[4], b); b = fmaf(m1.y, ww[5], b);
          b = fmaf(m1.z, ww[6], b); b = fmaf(m1.w, ww[7], b);
          mV[n][v] = a; mW[n][v] = b;
        }
      }
    }
    #pragma unroll
    for (int n = 0; n < MNPB; ++n) {
      const float ss = mV[n][0] * mV[n][0] + mV[n][1] * mV[n][1] + mV[n][2] * mV[n][2];
      vn_lds[n][t] = sqrtf(ss + 1e-8f);
      sdot[n] = mV[n][0] * mW[n][0] + mV[n][1] * mW[n][1] + mV[n][2] * mW[n][2];
    }
  } // mV dies
  __syncthreads();

  // ---- h2 = silu([qnew, vn] @ Wm1 + bm1); thread t owns col t ----
  float acc[MNPB];
  {
    const float bv = bm1[t];
    #pragma unroll
    for (int n = 0; n < MNPB; ++n) acc[n] = bv;
  }
  // K = 0..127: qnew half, uniform global reads
  for (int k = 0; k < CC; k += 8) {
    float w[8];
    #pragma unroll
    for (int r = 0; r < 8; ++r) w[r] = Wm1[(size_t)(k + r) * CC + t];
    #pragma unroll
    for (int n = 0; n < MNPB; ++n) {
      const float* qrow = actq + (size_t)(node0 + n) * CC + k;   // uniform
      const float4 c0 = *reinterpret_cast<const float4*>(qrow);
      const float4 c1 = *reinterpret_cast<const float4*>(qrow + 4);
      acc[n] = fmaf(c0.x, w[0], acc[n]); acc[n] = fmaf(c0.y, w[1], acc[n]);
      acc[n] = fmaf(c0.z, w[2], acc[n]); acc[n] = fmaf(c0.w, w[3], acc[n]);
      acc[n] = fmaf(c1.x, w[4], acc[n]); acc[n] = fmaf(c1.y, w[5], acc[n]);
      acc[n] = fmaf(c1.z, w[6], acc[n]); acc[n] = fmaf(c1.w, w[7], acc[n]);
    }
  }
  // K = 128..255: vn half, from LDS
  for (int k = 0; k < CC; k += 8) {
    float w[8];
    #pragma unroll
    for (int r = 0; r < 8; ++r) w[r] = Wm1[(size_t)(CC + k + r) * CC + t];
    #pragma unroll
    for (int n = 0; n < MNPB; ++n) {
      const float4 c0 = *reinterpret_cast<const float4*>(&vn_lds[n][k]);
      const float4 c1 = *reinterpret_cast<const float4*>(&vn_lds[n][k + 4]);
      acc[n] = fmaf(c0.x, w[0], acc[n]); acc[n] = fmaf(c0.y, w[1], acc[n]);
      acc[n] = fmaf(c0.z, w[2], acc[n]); acc[n] = fmaf(c0.w, w[3], acc[n]);
      acc[n] = fmaf(c1.x, w[4], acc[n]); acc[n] = fmaf(c1.y, w[5], acc[n]);
      acc[n] = fmaf(c1.z, w[6], acc[n]); acc[n] = fmaf(c1.w, w[7], acc[n]);
    }
  }
  #pragma unroll
  for (int n = 0; n < MNPB; ++n) {
    const float v = acc[n];
    h2_lds[n][t] = v / (1.0f + expf(-v));
  }
  __syncthreads();

  // ---- y = h2 @ Wm2 + bm2; thread t owns cols t, 128+t, 256+t ----
  float y0[MNPB], y1[MNPB], y2[MNPB];
  {
    const float bb0 = bm2[t], bb1 = bm2[CC + t], bb2 = bm2[2 * CC + t];
    #pragma unroll
    for (int n = 0; n < MNPB; ++n) { y0[n] = bb0; y1[n] = bb1; y2[n] = bb2; }
  }
  for (int k = 0; k < CC; k += 8) {
    float w0[8], w1[8], w2[8];
    #pragma unroll
    for (int r = 0; r < 8; ++r) {
      const size_t row = (size_t)(k + r) * TC;
      w0[r] = Wm2[row + t];
      w1[r] = Wm2[row + CC + t];
      w2[r] = Wm2[row + 2 * CC + t];
    }
    #pragma unroll
    for (int n = 0; n < MNPB; ++n) {
      const float4 h0 = *reinterpret_cast<const float4*>(&h2_lds[n][k]);
      const float4 h1 = *reinterpret_cast<const float4*>(&h2_lds[n][k + 4]);
      y0[n] = fmaf(h0.x, w0[0], y0[n]); y0[n] = fmaf(h0.y, w0[1], y0[n]);
      y0[n] = fmaf(h0.z, w0[2], y0[n]); y0[n] = fmaf(h0.w, w0[3], y0[n]);
      y0[n] = fmaf(h1.x, w0[4], y0[n]); y0[n] = fmaf(h1.y, w0[5], y0[n]);
      y0[n] = fmaf(h1.z, w0[6], y0[n]); y0[n] = fmaf(h1.w, w0[7], y0[n]);
      y1[n] = fmaf(h0.x, w1[0], y1[n]); y1[n] = fmaf(h0.y, w1[1], y1[n]);
      y1[n] = fmaf(h0.z, w1[2], y1[n]); y1[n] = fmaf(h0.w, w1[3], y1[n]);
      y1[n] = fmaf(h1.x, w1[4], y1[n]); y1[n] = fmaf(h1.y, w1[5], y1[n]);
      y1[n] = fmaf(h1.z, w1[6], y1[n]); y1[n] = fmaf(h1.w, w1[7], y1[n]);
      y2[n] = fmaf(h0.x, w2[0], y2[n]); y2[n] = fmaf(h0.y, w2[1], y2[n]);
      y2[n] = fmaf(h0.z, w2[2], y2[n]); y2[n] = fmaf(h0.w, w2[3], y2[n]);
      y2[n] = fmaf(h1.x, w2[4], y2[n]); y2[n] = fmaf(h1.y, w2[5], y2[n]);
      y2[n] = fmaf(h1.z, w2[6], y2[n]); y2[n] = fmaf(h1.w, w2[7], y2[n]);
    }
  }

  // ---- epilogue (per-thread col t reads; each load feeds its own store) ----
  #pragma unroll
  for (int n = 0; n < MNPB; ++n) {
    const size_t qb = (size_t)(node0 + n) * CC;
    const float qnew = actq[qb + t];
    qout[qb + t] = qnew + y0[n] + y2[n] * sdot[n];
    const size_t mb = (size_t)(node0 + n) * TC;
    muout[mb + t]          = actmu[mb + t]          + y1[n] * mW[n][0];
    muout[mb + CC + t]     = actmu[mb + CC + t]     + y1[n] * mW[n][1];
    muout[mb + 2 * CC + t] = actmu[mb + 2 * CC + t] + y1[n] * mW[n][2];
  }
}

// ---------------------------------------------------------------------------
extern "C" void kernel_launch(void* const* d_in, const int* in_sizes, int n_in,
                              void* d_out, int out_size, void* d_ws, size_t ws_size,
                              hipStream_t stream) {
  const float* q     = (const float*)d_in[0];
  const float* mu    = (const float*)d_in[1];
  const int*   eidx  = (const int*)d_in[2];
  const float* ew    = (const float*)d_in[3];
  const float* evers = (const float*)d_in[4];
  const float* eattr = (const float*)d_in[5];
  const float* Wf    = (const float*)d_in[6];
  const float* bf    = (const float*)d_in[7];
  const float* W1    = (const float*)d_in[8];
  const float* b1    = (const float*)d_in[9];
  const float* W2    = (const float*)d_in[10];
  const float* b2    = (const float*)d_in[11];
  const float* Wmix  = (const float*)d_in[12];
  const float* Wm1   = (const float*)d_in[13];
  const float* bm1   = (const float*)d_in[14];
  const float* Wm2   = (const float*)d_in[15];
  const float* bm2   = (const float*)d_in[16];

  float* out   = (float*)d_out;
  float* qout  = out;                                // [N, C]
  float* muout = out + (size_t)NNODES * CC;          // [N, 3, C]

  // workspace layout: packed | x | counts | offsets
  float* packed   = (float*)d_ws;                           // [E*28] floats
  float* x        = packed + (size_t)NEDGES * PKF;          // [N*3C]
  int*   counts   = (int*)(x + (size_t)NNODES * TC);        // [N]
  int*   offsets  = counts + NNODES;                        // [N+1]
  const size_t need_packed =
      ((size_t)NEDGES * PKF + (size_t)NNODES * TC) * 4 + (2 * NNODES + 2) * 4 + 256;
  const bool use_packed = ws_size >= need_packed;

  if (use_packed) {
    zero_counts_kernel<<<(NNODES + 255) / 256, 256, 0, stream>>>(counts);
    hist_kernel<<<(NEDGES + 255) / 256, 256, 0, stream>>>(eidx, counts);
    scan_kernel<<<1, 512, 0, stream>>>(counts, offsets);
    pack_scatter_kernel<<<(NEDGES + 255) / 256, 256, 0, stream>>>(
        eidx, ew, evers, eattr, offsets, counts, packed);
    ctx_net_kernel<<<NNODES / CNPB, 128, 0, stream>>>(q, W1, b1, W2, b2, x);
    gather_packed_kernel<<<NNODES, GTH, 0, stream>>>(
        packed, Wf, bf, x, mu, q, offsets, qout, muout);
  } else {
    // fallback layout (x | counts | offsets | edge_list)
    float* xf        = (float*)d_ws;
    int*   countsf   = (int*)(xf + (size_t)NNODES * TC);
    int*   offsetsf  = countsf + NNODES;
    int*   edge_list = offsetsf + NNODES + 1;
    zero_counts_kernel<<<(NNODES + 255) / 256, 256, 0, stream>>>(countsf);
    hist_kernel<<<(NEDGES + 255) / 256, 256, 0, stream>>>(eidx, countsf);
    scan_kernel<<<1, 512, 0, stream>>>(countsf, offsetsf);
    scatter_kernel<<<(NEDGES + 255) / 256, 256, 0, stream>>>(eidx, offsetsf,
                                                             countsf, edge_list);
    ctx_net_kernel<<<NNODES / CNPB, 128, 0, stream>>>(q, W1, b1, W2, b2, xf);
    gather_list_kernel<<<NNODES, GTH, 0, stream>>>(eidx, ew, evers, eattr,
                                                   Wf, bf, xf, mu, q,
                                                   offsetsf, edge_list,
                                                   qout, muout);
  }
  mix_kernel2<<<NNODES / MNPB, 128, 0, stream>>>(Wmix, Wm1, bm1, Wm2, bm2,
                                                 qout, muout, qout, muout);
}